// Round 13
// baseline (323.547 us; speedup 1.0000x reference)
//
#include <hip/hip_runtime.h>
#include <hip/hip_fp16.h>
#include <math.h>

#define N_NODES 50000
#define N_EDGES 800000
#define NB 782            // ceil(50000/64) buckets of 64 dst nodes
#define CH 4096           // edges per k_bucket block
#define CAP 2048          // arena slots per bucket (Poisson(1024) -> 2x slack)
#define BUCKET_BLOCKS 196 // ceil(800000/4096)
#define CAST_BLOCKS 6250  // N_NODES*128/4/256
#define PREPW_BLOCKS 192  // 3 * 16384/256
#define FILL_GRID (NB + CAST_BLOCKS + PREPW_BLOCKS)
#define PLANE ((size_t)N_NODES * 32)  // fp16 elems per feature-slice plane

typedef _Float16 half8 __attribute__((ext_vector_type(8)));
typedef float floatx4 __attribute__((ext_vector_type(4)));
typedef unsigned uintx4 __attribute__((ext_vector_type(4)));

// ---- pass 1: LDS-staged bucket scatter into padded arena ------------------
__global__ __launch_bounds__(256) void k_bucket(const int* __restrict__ src,
                                                const int* __restrict__ dst,
                                                int* __restrict__ gcur,
                                                unsigned* __restrict__ arena) {
    __shared__ int cntA[NB];
    __shared__ int lofs[NB];
    __shared__ int gbase[NB];
    __shared__ int part[256];
    __shared__ unsigned buf[CH];
    const int t = threadIdx.x;
    const int ebase = blockIdx.x * CH;
    const int chunkN = min(CH, N_EDGES - ebase);

    for (int i = t; i < NB; i += 256) cntA[i] = 0;
    __syncthreads();
    for (int i = t; i < chunkN; i += 256)
        atomicAdd(&cntA[dst[ebase + i] >> 6], 1);
    __syncthreads();
    int c[4];
    int s = 0;
#pragma unroll
    for (int q = 0; q < 4; ++q) {
        int idx = t * 4 + q;
        c[q] = (idx < NB) ? cntA[idx] : 0;
        s += c[q];
    }
    part[t] = s;
    __syncthreads();
    for (int d = 1; d < 256; d <<= 1) {
        int u = (t >= d) ? part[t - d] : 0;
        __syncthreads();
        part[t] += u;
        __syncthreads();
    }
    int run = (t > 0) ? part[t - 1] : 0;
#pragma unroll
    for (int q = 0; q < 4; ++q) {
        int idx = t * 4 + q;
        if (idx < NB) {
            lofs[idx] = run;
            run += c[q];
            gbase[idx] = (c[q] > 0) ? atomicAdd(&gcur[idx], c[q]) : 0;
            cntA[idx] = 0;  // reuse as placement cursor
        }
    }
    __syncthreads();
    for (int i = t; i < chunkN; i += 256) {
        int d = dst[ebase + i];
        int sv = src[ebase + i];
        int b = d >> 6;
        int pos = atomicAdd(&cntA[b], 1);
        buf[lofs[b] + pos] = ((unsigned)d << 16) | (unsigned)sv;
    }
    __syncthreads();
    for (int i = t; i < chunkN; i += 256) {
        unsigned v = buf[i];
        int b = (int)(v >> 16) >> 6;
        int q = i - lofs[b];
        int p = gbase[b] + q;
        if (p < CAP) arena[((size_t)b << 11) + p] = v;
    }
}

// ---- pass 2 (fused): bucket finalize | x->fp16 cast | W->fp16 W^T ---------
__global__ __launch_bounds__(256) void k_fill3prep(
    const unsigned* __restrict__ arena, const int* __restrict__ gcur,
    unsigned* __restrict__ packed, float* __restrict__ dinv,
    int* __restrict__ eidx, const float* __restrict__ x,
    __half* __restrict__ xh, const float* __restrict__ W0,
    const float* __restrict__ W1, const float* __restrict__ W2,
    __half* __restrict__ WT) {
    const int t = threadIdx.x;
    if (blockIdx.x < NB) {
        const int b = blockIdx.x;
        __shared__ int cnt64[64];
        __shared__ int cur64[64];
        if (t < 64) cnt64[t] = 0;
        __syncthreads();
        const int seglen = min(gcur[b], CAP);
        const unsigned* seg = arena + ((size_t)b << 11);
        for (int i = t; i < seglen; i += 256)
            atomicAdd(&cnt64[(seg[i] >> 16) & 63], 1);
        __syncthreads();
        if (t < 64) {  // one wave: prefix scan of 64 counts
            int v = cnt64[t];
            int p = v;
#pragma unroll
            for (int d = 1; d < 64; d <<= 1) {
                int u = __shfl_up(p, d, 64);
                if (t >= d) p += u;
            }
            int excl = p - v;
            int node = b * 64 + t;
            if (node < N_NODES) {
                packed[node] =
                    ((unsigned)((b << 11) + excl) << 11) | (unsigned)v;
                dinv[node] = rsqrtf((float)v + 2.0f);  // improved: +2
            }
            cur64[t] = excl;
        }
        __syncthreads();
        const int base = b << 11;
        for (int i = t; i < seglen; i += 256) {
            unsigned v = seg[i];
            int d = (int)(v >> 16) & 63;
            int pos = atomicAdd(&cur64[d], 1);
            eidx[base + pos] = (int)(v & 0xFFFFu);
        }
    } else if (blockIdx.x < NB + CAST_BLOCKS) {
        int i = (blockIdx.x - NB) * 256 + t;  // float4-granular, exact
        float4 v = *(const float4*)&x[(size_t)i * 4];
        union { ushort4 u; __half h[4]; } p;
        p.h[0] = __float2half(v.x); p.h[1] = __float2half(v.y);
        p.h[2] = __float2half(v.z); p.h[3] = __float2half(v.w);
        *(ushort4*)&xh[(size_t)i * 4] = p.u;
    } else {
        int idx = blockIdx.x - NB - CAST_BLOCKS;  // 0..191
        int which = idx >> 6;
        const float* W = (which == 0) ? W0 : (which == 1) ? W1 : W2;
        int i = (idx & 63) * 256 + t;  // 16384 per matrix: i = k*128 + n
        int k = i >> 7, n = i & 127;
        int np = ((n & 7) << 4) + (n >> 3);  // inverse of perm(n')=(n'&15)*8+(n'>>4)
        WT[which * 128 * 128 + np * 128 + k] = __float2half(W[i]);
    }
}

// ====== MFMA GEMM: Hs = fp16((Ah @ W) * dinv[row]), SLICED output ==========
// Slice plane = feature block of 32; lane m writes slice m>>2, offset (m&3)*8.
__global__ __launch_bounds__(256) void k_gemm_mfma(const __half* __restrict__ Ah,
                                                   const __half* __restrict__ WT,
                                                   const float* __restrict__ dinv,
                                                   __half* __restrict__ hs) {
    const int tid = threadIdx.x;
    const int wave = tid >> 6;
    const int lane = tid & 63;
    const int m = lane & 15;
    const int quad = lane >> 4;
    const int rowA = blockIdx.x * 64 + wave * 16 + m;
    const int rA = (rowA < N_NODES) ? rowA : 0;
    const __half* arow = Ah + (size_t)rA * 128 + quad * 8;

    floatx4 acc[8] = {};
#pragma unroll
    for (int kb = 0; kb < 4; ++kb) {
        half8 af = __builtin_nontemporal_load((const half8*)(arow + kb * 32));
#pragma unroll
        for (int nt = 0; nt < 8; ++nt) {
            half8 bf = *(const half8*)(WT + (size_t)(nt * 16 + m) * 128 +
                                       kb * 32 + quad * 8);
            acc[nt] = __builtin_amdgcn_mfma_f32_16x16x32_f16(af, bf, acc[nt],
                                                             0, 0, 0);
        }
    }
    const int rb = blockIdx.x * 64 + wave * 16 + quad * 4;
    const int sp = m >> 2;
    const int off = (m & 3) * 8;
#pragma unroll
    for (int r = 0; r < 4; ++r) {
        int row = rb + r;
        if (row < N_NODES) {
            float dv = dinv[row];
            union { uintx4 u; __half h[8]; } pk;
#pragma unroll
            for (int nt = 0; nt < 8; ++nt)
                pk.h[nt] = __float2half(acc[nt][r] * dv);
            *(uintx4*)(hs + sp * PLANE + (size_t)row * 32 + off) = pk.u;
        }
    }
}

// ---- dense transform, F_out = 16 (last layer): fp16 in, fp32 out ----------
__global__ __launch_bounds__(256) void k_gemm16(const __half* __restrict__ in,
                                                const float* __restrict__ W,
                                                const float* __restrict__ dinv,
                                                float* __restrict__ hs) {
    __shared__ float Wt[16 * 132];
    const int tid = threadIdx.x;
    for (int i = tid; i < 128 * 16; i += 256) {
        int k = i >> 4, c = i & 15;
        Wt[c * 132 + k] = W[i];
    }
    __syncthreads();
    int gid = blockIdx.x * 256 + tid;  // grid exactly 50000*16
    int r = gid >> 4, c = gid & 15;
    const __half* arow = &in[(size_t)r * 128];
    const float* wrow = &Wt[c * 132];
    float acc = 0.f;
#pragma unroll
    for (int k0 = 0; k0 < 128; k0 += 8) {
        union { uint4 u; __half2 h2[4]; } p;
        p.u = *(const uint4*)&arow[k0];
#pragma unroll
        for (int q = 0; q < 4; ++q) {
            float2 a = __half22float2(p.h2[q]);
            acc += a.x * wrow[k0 + 2 * q] + a.y * wrow[k0 + 2 * q + 1];
        }
    }
    hs[gid] = acc * dinv[r];
}

// ====== SLICED aggregate + epilogue: 4 lanes/node, 1 slice/block ===========
__device__ __forceinline__ void acc8(const __half* p, float* acc) {
    union { uint4 u; __half2 h2[4]; } t;
    t.u = *(const uint4*)p;
#pragma unroll
    for (int q = 0; q < 4; ++q) {
        float2 v = __half22float2(t.h2[q]);
        acc[2 * q] += v.x;
        acc[2 * q + 1] += v.y;
    }
}
__device__ __forceinline__ void store8_nt(__half* p, const float* o) {
    union { uintx4 u; __half h[8]; } c;
#pragma unroll
    for (int j = 0; j < 8; ++j) c.h[j] = __float2half(o[j]);
    __builtin_nontemporal_store(c.u, (uintx4*)p);
}

// out[r][s*32+l4*8..+8) = relu(dinv*(2*Hs[r]+sum Hs[src]) + b)
__global__ __launch_bounds__(256) void k_gather_s(const unsigned* __restrict__ packed,
                                                  const int* __restrict__ eidx,
                                                  const __half* __restrict__ hs,
                                                  const float* __restrict__ dinv,
                                                  const float* __restrict__ bias,
                                                  __half* __restrict__ out) {
    const int s = blockIdx.x & 3;        // slice; XCD round-robin pins 1/XCD
    const int nb = blockIdx.x >> 2;
    const int t = threadIdx.x;
    const int r = nb * 64 + (t >> 2);
    if (r >= N_NODES) return;
    const int l4 = t & 3;
    const int fl = l4 * 8;
    const __half* plane = hs + s * PLANE;
    float acc[8];
    {
        union { uint4 u; __half2 h2[4]; } p;
        p.u = *(const uint4*)&plane[(size_t)r * 32 + fl];
#pragma unroll
        for (int q = 0; q < 4; ++q) {
            float2 v = __half22float2(p.h2[q]);
            acc[2 * q] = 2.f * v.x;
            acc[2 * q + 1] = 2.f * v.y;
        }
    }
    unsigned pk = packed[r];
    int i = (int)(pk >> 11);
    int end = i + (int)(pk & 2047u);
    // 8-edge batches: 2 index loads, 8 row loads in flight
    for (; i + 8 <= end; i += 8) {
        int mya = __builtin_nontemporal_load(&eidx[i + l4]);
        int myb = __builtin_nontemporal_load(&eidx[i + 4 + l4]);
#pragma unroll
        for (int j = 0; j < 4; ++j) {
            int s0 = __shfl(mya, j, 4);
            acc8(&plane[(size_t)s0 * 32 + fl], acc);
        }
#pragma unroll
        for (int j = 0; j < 4; ++j) {
            int s0 = __shfl(myb, j, 4);
            acc8(&plane[(size_t)s0 * 32 + fl], acc);
        }
    }
    if (i < end) {
        int n = end - i;
        int mya = (l4 < n) ? eidx[i + l4] : 0;
        int myb = (l4 + 4 < n) ? eidx[i + 4 + l4] : 0;
        int n0 = min(n, 4);
        for (int j = 0; j < n0; ++j) {
            int s0 = __shfl(mya, j, 4);
            acc8(&plane[(size_t)s0 * 32 + fl], acc);
        }
        for (int j = 0; j < n - 4; ++j) {
            int s0 = __shfl(myb, j, 4);
            acc8(&plane[(size_t)s0 * 32 + fl], acc);
        }
    }
    float dv = dinv[r];
    float o[8];
#pragma unroll
    for (int j = 0; j < 8; ++j)
        o[j] = fmaxf(dv * acc[j] + bias[s * 32 + fl + j], 0.f);
    store8_nt(out + (size_t)r * 128 + s * 32 + fl, o);
}

// ====== fp32 gather for the last (F=16) layer ======
__global__ __launch_bounds__(256) void k_gather4(const unsigned* __restrict__ packed,
                                                 const int* __restrict__ eidx,
                                                 const float* __restrict__ hs,
                                                 const float* __restrict__ dinv,
                                                 const float* __restrict__ bias,
                                                 float* __restrict__ out) {
    int tid = blockIdx.x * 256 + threadIdx.x;
    int r = tid >> 2;
    if (r >= N_NODES) return;
    int l = tid & 3;
    int f = l * 4;
    float4 h = *(const float4*)&hs[(size_t)r * 16 + f];
    float ax = 2.f * h.x, ay = 2.f * h.y, az = 2.f * h.z, aw = 2.f * h.w;
    unsigned pk = packed[r];
    int i = (int)(pk >> 11);
    int end = i + (int)(pk & 2047u);
    for (; i + 4 <= end; i += 4) {
        int my = eidx[i + l];
#pragma unroll
        for (int j = 0; j < 4; ++j) {
            int s = __shfl(my, j, 4);
            float4 v = *(const float4*)&hs[(size_t)s * 16 + f];
            ax += v.x; ay += v.y; az += v.z; aw += v.w;
        }
    }
    if (i < end) {
        int n = end - i;
        int my = (l < n) ? eidx[i + l] : 0;
        for (int j = 0; j < n; ++j) {
            int s = __shfl(my, j, 4);
            float4 v = *(const float4*)&hs[(size_t)s * 16 + f];
            ax += v.x; ay += v.y; az += v.z; aw += v.w;
        }
    }
    float dv = dinv[r];
    float v0 = tanhf(dv * ax + bias[f + 0]);
    float v1 = tanhf(dv * ay + bias[f + 1]);
    float v2 = tanhf(dv * az + bias[f + 2]);
    float v3 = tanhf(dv * aw + bias[f + 3]);
    floatx4 o = {v0, v1, v2, v3};
    __builtin_nontemporal_store(o, (floatx4*)&out[(size_t)r * 16 + f]);
}

extern "C" void kernel_launch(void* const* d_in, const int* in_sizes, int n_in,
                              void* d_out, int out_size, void* d_ws, size_t ws_size,
                              hipStream_t stream) {
    const float* x  = (const float*)d_in[0];
    const int* ei   = (const int*)d_in[1];
    const float* W0 = (const float*)d_in[2];
    const float* b0 = (const float*)d_in[3];
    const float* W1 = (const float*)d_in[4];
    const float* b1 = (const float*)d_in[5];
    const float* W2 = (const float*)d_in[6];
    const float* b2 = (const float*)d_in[7];
    const float* W3 = (const float*)d_in[8];
    const float* b3 = (const float*)d_in[9];
    const int* src = ei;
    const int* dst = ei + N_EDGES;

    // ws layout (16B-aligned):
    __half* A      = (__half*)d_ws;                        // 50000*128 f16
    __half* Hh     = A + (size_t)N_NODES * 128;            // 4 slice planes
    __half* WT     = Hh + (size_t)N_NODES * 128;           // 3*128*128 f16
    float*  H16    = (float*)(WT + 3 * 128 * 128);         // 50000*16 f32
    float*  dinv   = H16 + (size_t)N_NODES * 16;           // 50000
    unsigned* packed = (unsigned*)(dinv + N_NODES);        // 50000
    int*    gcur   = (int*)(packed + N_NODES);             // 1024 (NB padded)
    int*    eidx   = gcur + 1024;                          // NB*CAP
    unsigned* arena = (unsigned*)(eidx + NB * CAP);        // NB*CAP

    // ---- CSR build + prep (every call; ws is re-poisoned) ----
    (void)hipMemsetAsync(gcur, 0, 1024 * sizeof(int), stream);
    k_bucket<<<BUCKET_BLOCKS, 256, 0, stream>>>(src, dst, gcur, arena);
    k_fill3prep<<<FILL_GRID, 256, 0, stream>>>(arena, gcur, packed, dinv,
                                               eidx, x, A, W0, W1, W2, WT);

    const int GB = (N_NODES + 63) / 64;  // mfma gemm blocks (64 rows each)
    const int SGB = 4 * NB;              // sliced gather blocks (4 x 782)
    // ---- layer 0 ----
    k_gemm_mfma<<<GB, 256, 0, stream>>>(A, WT, dinv, Hh);
    k_gather_s<<<SGB, 256, 0, stream>>>(packed, eidx, Hh, dinv, b0, A);
    // ---- layer 1 ----
    k_gemm_mfma<<<GB, 256, 0, stream>>>(A, WT + 128 * 128, dinv, Hh);
    k_gather_s<<<SGB, 256, 0, stream>>>(packed, eidx, Hh, dinv, b1, A);
    // ---- layer 2 ----
    k_gemm_mfma<<<GB, 256, 0, stream>>>(A, WT + 2 * 128 * 128, dinv, Hh);
    k_gather_s<<<SGB, 256, 0, stream>>>(packed, eidx, Hh, dinv, b2, A);
    // ---- layer 3 (128 -> 16, tanh) ----
    k_gemm16<<<N_NODES * 16 / 256, 256, 0, stream>>>(A, W3, dinv, H16);
    k_gather4<<<(N_NODES * 4 + 255) / 256, 256, 0, stream>>>(
        packed, eidx, H16, dinv, b3, (float*)d_out);
}

// Round 14
// 303.900 us; speedup vs baseline: 1.0646x; 1.0646x over previous
//
#include <hip/hip_runtime.h>
#include <hip/hip_fp16.h>
#include <math.h>

#define N_NODES 50000
#define N_EDGES 800000
#define NB 782            // ceil(50000/64) buckets of 64 dst nodes
#define CH 4096           // edges per k_bucket block
#define CAP 2048          // arena slots per bucket (Poisson(1024) -> 2x slack)
#define BUCKET_BLOCKS 196 // ceil(800000/4096)
#define CAST_BLOCKS 6250  // N_NODES*128/4/256
#define PREPW_BLOCKS 192  // 3 * 16384/256
#define FILL_GRID (NB + CAST_BLOCKS + PREPW_BLOCKS)
#define PLANE2 ((size_t)N_NODES * 64)  // fp16 elems per 64-feature plane (128B rows)

typedef _Float16 half8 __attribute__((ext_vector_type(8)));
typedef float floatx4 __attribute__((ext_vector_type(4)));
typedef unsigned uintx4 __attribute__((ext_vector_type(4)));

// ---- pass 1: LDS-staged bucket scatter into padded arena ------------------
__global__ __launch_bounds__(256) void k_bucket(const int* __restrict__ src,
                                                const int* __restrict__ dst,
                                                int* __restrict__ gcur,
                                                unsigned* __restrict__ arena) {
    __shared__ int cntA[NB];
    __shared__ int lofs[NB];
    __shared__ int gbase[NB];
    __shared__ int part[256];
    __shared__ unsigned buf[CH];
    const int t = threadIdx.x;
    const int ebase = blockIdx.x * CH;
    const int chunkN = min(CH, N_EDGES - ebase);

    for (int i = t; i < NB; i += 256) cntA[i] = 0;
    __syncthreads();
    for (int i = t; i < chunkN; i += 256)
        atomicAdd(&cntA[dst[ebase + i] >> 6], 1);
    __syncthreads();
    int c[4];
    int s = 0;
#pragma unroll
    for (int q = 0; q < 4; ++q) {
        int idx = t * 4 + q;
        c[q] = (idx < NB) ? cntA[idx] : 0;
        s += c[q];
    }
    part[t] = s;
    __syncthreads();
    for (int d = 1; d < 256; d <<= 1) {
        int u = (t >= d) ? part[t - d] : 0;
        __syncthreads();
        part[t] += u;
        __syncthreads();
    }
    int run = (t > 0) ? part[t - 1] : 0;
#pragma unroll
    for (int q = 0; q < 4; ++q) {
        int idx = t * 4 + q;
        if (idx < NB) {
            lofs[idx] = run;
            run += c[q];
            gbase[idx] = (c[q] > 0) ? atomicAdd(&gcur[idx], c[q]) : 0;
            cntA[idx] = 0;  // reuse as placement cursor
        }
    }
    __syncthreads();
    for (int i = t; i < chunkN; i += 256) {
        int d = dst[ebase + i];
        int sv = src[ebase + i];
        int b = d >> 6;
        int pos = atomicAdd(&cntA[b], 1);
        buf[lofs[b] + pos] = ((unsigned)d << 16) | (unsigned)sv;
    }
    __syncthreads();
    for (int i = t; i < chunkN; i += 256) {
        unsigned v = buf[i];
        int b = (int)(v >> 16) >> 6;
        int q = i - lofs[b];
        int p = gbase[b] + q;
        if (p < CAP) arena[((size_t)b << 11) + p] = v;
    }
}

// ---- pass 2 (fused): bucket finalize | x->fp16 cast | W->fp16 W^T ---------
__global__ __launch_bounds__(256) void k_fill3prep(
    const unsigned* __restrict__ arena, const int* __restrict__ gcur,
    unsigned* __restrict__ packed, float* __restrict__ dinv,
    int* __restrict__ eidx, const float* __restrict__ x,
    __half* __restrict__ xh, const float* __restrict__ W0,
    const float* __restrict__ W1, const float* __restrict__ W2,
    __half* __restrict__ WT) {
    const int t = threadIdx.x;
    if (blockIdx.x < NB) {
        const int b = blockIdx.x;
        __shared__ int cnt64[64];
        __shared__ int cur64[64];
        if (t < 64) cnt64[t] = 0;
        __syncthreads();
        const int seglen = min(gcur[b], CAP);
        const unsigned* seg = arena + ((size_t)b << 11);
        for (int i = t; i < seglen; i += 256)
            atomicAdd(&cnt64[(seg[i] >> 16) & 63], 1);
        __syncthreads();
        if (t < 64) {  // one wave: prefix scan of 64 counts
            int v = cnt64[t];
            int p = v;
#pragma unroll
            for (int d = 1; d < 64; d <<= 1) {
                int u = __shfl_up(p, d, 64);
                if (t >= d) p += u;
            }
            int excl = p - v;
            int node = b * 64 + t;
            if (node < N_NODES) {
                packed[node] =
                    ((unsigned)((b << 11) + excl) << 11) | (unsigned)v;
                dinv[node] = rsqrtf((float)v + 2.0f);  // improved: +2
            }
            cur64[t] = excl;
        }
        __syncthreads();
        const int base = b << 11;
        for (int i = t; i < seglen; i += 256) {
            unsigned v = seg[i];
            int d = (int)(v >> 16) & 63;
            int pos = atomicAdd(&cur64[d], 1);
            eidx[base + pos] = (int)(v & 0xFFFFu);
        }
    } else if (blockIdx.x < NB + CAST_BLOCKS) {
        int i = (blockIdx.x - NB) * 256 + t;  // float4-granular, exact
        float4 v = *(const float4*)&x[(size_t)i * 4];
        union { ushort4 u; __half h[4]; } p;
        p.h[0] = __float2half(v.x); p.h[1] = __float2half(v.y);
        p.h[2] = __float2half(v.z); p.h[3] = __float2half(v.w);
        *(ushort4*)&xh[(size_t)i * 4] = p.u;
    } else {
        int idx = blockIdx.x - NB - CAST_BLOCKS;  // 0..191
        int which = idx >> 6;
        const float* W = (which == 0) ? W0 : (which == 1) ? W1 : W2;
        int i = (idx & 63) * 256 + t;  // 16384 per matrix: i = k*128 + n
        int k = i >> 7, n = i & 127;
        int np = ((n & 7) << 4) + (n >> 3);  // inverse of perm(n')=(n'&15)*8+(n'>>4)
        WT[which * 128 * 128 + np * 128 + k] = __float2half(W[i]);
    }
}

// ====== MFMA GEMM: Hs = fp16((Ah @ W) * dinv[row]), 2-plane output =========
// Lane m: plane m>>3, in-plane offset (m&7)*8 -> 16B stores, 128B rows.
__global__ __launch_bounds__(256) void k_gemm_mfma(const __half* __restrict__ Ah,
                                                   const __half* __restrict__ WT,
                                                   const float* __restrict__ dinv,
                                                   __half* __restrict__ hs) {
    const int tid = threadIdx.x;
    const int wave = tid >> 6;
    const int lane = tid & 63;
    const int m = lane & 15;
    const int quad = lane >> 4;
    const int rowA = blockIdx.x * 64 + wave * 16 + m;
    const int rA = (rowA < N_NODES) ? rowA : 0;
    const __half* arow = Ah + (size_t)rA * 128 + quad * 8;

    floatx4 acc[8] = {};
#pragma unroll
    for (int kb = 0; kb < 4; ++kb) {
        half8 af = __builtin_nontemporal_load((const half8*)(arow + kb * 32));
#pragma unroll
        for (int nt = 0; nt < 8; ++nt) {
            half8 bf = *(const half8*)(WT + (size_t)(nt * 16 + m) * 128 +
                                       kb * 32 + quad * 8);
            acc[nt] = __builtin_amdgcn_mfma_f32_16x16x32_f16(af, bf, acc[nt],
                                                             0, 0, 0);
        }
    }
    const int rb = blockIdx.x * 64 + wave * 16 + quad * 4;
    __half* base = hs + (m >> 3) * PLANE2 + (m & 7) * 8;
#pragma unroll
    for (int r = 0; r < 4; ++r) {
        int row = rb + r;
        if (row < N_NODES) {
            float dv = dinv[row];
            union { uintx4 u; __half h[8]; } pk;
#pragma unroll
            for (int nt = 0; nt < 8; ++nt)
                pk.h[nt] = __float2half(acc[nt][r] * dv);
            *(uintx4*)(base + (size_t)row * 64) = pk.u;
        }
    }
}

// ---- dense transform, F_out = 16 (last layer): fp16 in, fp32 out ----------
__global__ __launch_bounds__(256) void k_gemm16(const __half* __restrict__ in,
                                                const float* __restrict__ W,
                                                const float* __restrict__ dinv,
                                                float* __restrict__ hs) {
    __shared__ float Wt[16 * 132];
    const int tid = threadIdx.x;
    for (int i = tid; i < 128 * 16; i += 256) {
        int k = i >> 4, c = i & 15;
        Wt[c * 132 + k] = W[i];
    }
    __syncthreads();
    int gid = blockIdx.x * 256 + tid;  // grid exactly 50000*16
    int r = gid >> 4, c = gid & 15;
    const __half* arow = &in[(size_t)r * 128];
    const float* wrow = &Wt[c * 132];
    float acc = 0.f;
#pragma unroll
    for (int k0 = 0; k0 < 128; k0 += 8) {
        union { uint4 u; __half2 h2[4]; } p;
        p.u = *(const uint4*)&arow[k0];
#pragma unroll
        for (int q = 0; q < 4; ++q) {
            float2 a = __half22float2(p.h2[q]);
            acc += a.x * wrow[k0 + 2 * q] + a.y * wrow[k0 + 2 * q + 1];
        }
    }
    hs[gid] = acc * dinv[r];
}

// ====== 2-plane sliced aggregate + epilogue: 8 lanes/node ==================
__device__ __forceinline__ void acc8(const __half* p, float* acc) {
    union { uint4 u; __half2 h2[4]; } t;
    t.u = *(const uint4*)p;
#pragma unroll
    for (int q = 0; q < 4; ++q) {
        float2 v = __half22float2(t.h2[q]);
        acc[2 * q] += v.x;
        acc[2 * q + 1] += v.y;
    }
}
__device__ __forceinline__ void store8_nt(__half* p, const float* o) {
    union { uintx4 u; __half h[8]; } c;
#pragma unroll
    for (int j = 0; j < 8; ++j) c.h[j] = __float2half(o[j]);
    __builtin_nontemporal_store(c.u, (uintx4*)p);
}

// out[r][s*64 + l8*8 ..+8) = relu(dinv*(2*Hs[r]+sum Hs[src]) + b)
__global__ __launch_bounds__(256) void k_gather_s2(const unsigned* __restrict__ packed,
                                                   const int* __restrict__ eidx,
                                                   const __half* __restrict__ hs,
                                                   const float* __restrict__ dinv,
                                                   const float* __restrict__ bias,
                                                   __half* __restrict__ out) {
    const int s = blockIdx.x & 1;   // plane; round-robin pins planes to XCDs
    const int nb = blockIdx.x >> 1;
    const int t = threadIdx.x;
    const int r = nb * 32 + (t >> 3);
    if (r >= N_NODES) return;
    const int l8 = t & 7;
    const int fl = l8 * 8;
    const __half* plane = hs + s * PLANE2;
    float acc[8];
    {
        union { uint4 u; __half2 h2[4]; } p;
        p.u = *(const uint4*)&plane[(size_t)r * 64 + fl];
#pragma unroll
        for (int q = 0; q < 4; ++q) {
            float2 v = __half22float2(p.h2[q]);
            acc[2 * q] = 2.f * v.x;
            acc[2 * q + 1] = 2.f * v.y;
        }
    }
    unsigned pk = packed[r];
    int i = (int)(pk >> 11);
    int end = i + (int)(pk & 2047u);
    // 16-edge batches: 2 index loads, 16 row loads in flight
    for (; i + 16 <= end; i += 16) {
        int mya = __builtin_nontemporal_load(&eidx[i + l8]);
        int myb = __builtin_nontemporal_load(&eidx[i + 8 + l8]);
#pragma unroll
        for (int j = 0; j < 8; ++j) {
            int s0 = __shfl(mya, j, 8);
            acc8(&plane[(size_t)s0 * 64 + fl], acc);
        }
#pragma unroll
        for (int j = 0; j < 8; ++j) {
            int s0 = __shfl(myb, j, 8);
            acc8(&plane[(size_t)s0 * 64 + fl], acc);
        }
    }
    for (; i + 8 <= end; i += 8) {
        int mya = __builtin_nontemporal_load(&eidx[i + l8]);
#pragma unroll
        for (int j = 0; j < 8; ++j) {
            int s0 = __shfl(mya, j, 8);
            acc8(&plane[(size_t)s0 * 64 + fl], acc);
        }
    }
    if (i < end) {
        int n = end - i;
        int mya = (l8 < n) ? eidx[i + l8] : 0;
        for (int j = 0; j < n; ++j) {
            int s0 = __shfl(mya, j, 8);
            acc8(&plane[(size_t)s0 * 64 + fl], acc);
        }
    }
    float dv = dinv[r];
    float o[8];
#pragma unroll
    for (int j = 0; j < 8; ++j)
        o[j] = fmaxf(dv * acc[j] + bias[s * 64 + fl + j], 0.f);
    store8_nt(out + (size_t)r * 128 + s * 64 + fl, o);
}

// ====== fp32 gather for the last (F=16) layer ======
__global__ __launch_bounds__(256) void k_gather4(const unsigned* __restrict__ packed,
                                                 const int* __restrict__ eidx,
                                                 const float* __restrict__ hs,
                                                 const float* __restrict__ dinv,
                                                 const float* __restrict__ bias,
                                                 float* __restrict__ out) {
    int tid = blockIdx.x * 256 + threadIdx.x;
    int r = tid >> 2;
    if (r >= N_NODES) return;
    int l = tid & 3;
    int f = l * 4;
    float4 h = *(const float4*)&hs[(size_t)r * 16 + f];
    float ax = 2.f * h.x, ay = 2.f * h.y, az = 2.f * h.z, aw = 2.f * h.w;
    unsigned pk = packed[r];
    int i = (int)(pk >> 11);
    int end = i + (int)(pk & 2047u);
    for (; i + 4 <= end; i += 4) {
        int my = eidx[i + l];
#pragma unroll
        for (int j = 0; j < 4; ++j) {
            int s = __shfl(my, j, 4);
            float4 v = *(const float4*)&hs[(size_t)s * 16 + f];
            ax += v.x; ay += v.y; az += v.z; aw += v.w;
        }
    }
    if (i < end) {
        int n = end - i;
        int my = (l < n) ? eidx[i + l] : 0;
        for (int j = 0; j < n; ++j) {
            int s = __shfl(my, j, 4);
            float4 v = *(const float4*)&hs[(size_t)s * 16 + f];
            ax += v.x; ay += v.y; az += v.z; aw += v.w;
        }
    }
    float dv = dinv[r];
    float v0 = tanhf(dv * ax + bias[f + 0]);
    float v1 = tanhf(dv * ay + bias[f + 1]);
    float v2 = tanhf(dv * az + bias[f + 2]);
    float v3 = tanhf(dv * aw + bias[f + 3]);
    floatx4 o = {v0, v1, v2, v3};
    __builtin_nontemporal_store(o, (floatx4*)&out[(size_t)r * 16 + f]);
}

extern "C" void kernel_launch(void* const* d_in, const int* in_sizes, int n_in,
                              void* d_out, int out_size, void* d_ws, size_t ws_size,
                              hipStream_t stream) {
    const float* x  = (const float*)d_in[0];
    const int* ei   = (const int*)d_in[1];
    const float* W0 = (const float*)d_in[2];
    const float* b0 = (const float*)d_in[3];
    const float* W1 = (const float*)d_in[4];
    const float* b1 = (const float*)d_in[5];
    const float* W2 = (const float*)d_in[6];
    const float* b2 = (const float*)d_in[7];
    const float* W3 = (const float*)d_in[8];
    const float* b3 = (const float*)d_in[9];
    const int* src = ei;
    const int* dst = ei + N_EDGES;

    // ws layout (16B-aligned):
    __half* A      = (__half*)d_ws;                        // 50000*128 f16
    __half* Hh     = A + (size_t)N_NODES * 128;            // 2 planes of 64
    __half* WT     = Hh + (size_t)N_NODES * 128;           // 3*128*128 f16
    float*  H16    = (float*)(WT + 3 * 128 * 128);         // 50000*16 f32
    float*  dinv   = H16 + (size_t)N_NODES * 16;           // 50000
    unsigned* packed = (unsigned*)(dinv + N_NODES);        // 50000
    int*    gcur   = (int*)(packed + N_NODES);             // 1024 (NB padded)
    int*    eidx   = gcur + 1024;                          // NB*CAP
    unsigned* arena = (unsigned*)(eidx + NB * CAP);        // NB*CAP

    // ---- CSR build + prep (every call; ws is re-poisoned) ----
    (void)hipMemsetAsync(gcur, 0, 1024 * sizeof(int), stream);
    k_bucket<<<BUCKET_BLOCKS, 256, 0, stream>>>(src, dst, gcur, arena);
    k_fill3prep<<<FILL_GRID, 256, 0, stream>>>(arena, gcur, packed, dinv,
                                               eidx, x, A, W0, W1, W2, WT);

    const int GB = (N_NODES + 63) / 64;   // mfma gemm blocks (64 rows each)
    const int SGB = 2 * ((N_NODES + 31) / 32);  // sliced gather blocks
    // ---- layer 0 ----
    k_gemm_mfma<<<GB, 256, 0, stream>>>(A, WT, dinv, Hh);
    k_gather_s2<<<SGB, 256, 0, stream>>>(packed, eidx, Hh, dinv, b0, A);
    // ---- layer 1 ----
    k_gemm_mfma<<<GB, 256, 0, stream>>>(A, WT + 128 * 128, dinv, Hh);
    k_gather_s2<<<SGB, 256, 0, stream>>>(packed, eidx, Hh, dinv, b1, A);
    // ---- layer 2 ----
    k_gemm_mfma<<<GB, 256, 0, stream>>>(A, WT + 2 * 128 * 128, dinv, Hh);
    k_gather_s2<<<SGB, 256, 0, stream>>>(packed, eidx, Hh, dinv, b2, A);
    // ---- layer 3 (128 -> 16, tanh) ----
    k_gemm16<<<N_NODES * 16 / 256, 256, 0, stream>>>(A, W3, dinv, H16);
    k_gather4<<<(N_NODES * 4 + 255) / 256, 256, 0, stream>>>(
        packed, eidx, H16, dinv, b3, (float*)d_out);
}

// Round 15
// 303.890 us; speedup vs baseline: 1.0647x; 1.0000x over previous
//
#include <hip/hip_runtime.h>
#include <hip/hip_fp16.h>
#include <math.h>

#define N_NODES 50000
#define N_EDGES 800000
#define NB 782            // ceil(50000/64) buckets of 64 dst nodes
#define CH 4096           // edges per k_bucket block
#define CAP 2048          // arena slots per bucket (Poisson(1024) -> 2x slack)
#define BUCKET_BLOCKS 196 // ceil(800000/4096)
#define CAST_BLOCKS 6250  // N_NODES*128/4/256
#define PREPW_BLOCKS 192  // 3 * 16384/256
#define FILL_GRID (NB + CAST_BLOCKS + PREPW_BLOCKS)
#define PLANE2 ((size_t)N_NODES * 64)  // fp16 elems per 64-feature plane (128B rows)

typedef _Float16 half8 __attribute__((ext_vector_type(8)));
typedef float floatx4 __attribute__((ext_vector_type(4)));
typedef unsigned uintx4 __attribute__((ext_vector_type(4)));

// ---- pass 1: LDS-staged bucket scatter into padded arena ------------------
__global__ __launch_bounds__(256) void k_bucket(const int* __restrict__ src,
                                                const int* __restrict__ dst,
                                                int* __restrict__ gcur,
                                                unsigned* __restrict__ arena) {
    __shared__ int cntA[NB];
    __shared__ int lofs[NB];
    __shared__ int gbase[NB];
    __shared__ int part[256];
    __shared__ unsigned buf[CH];
    const int t = threadIdx.x;
    const int ebase = blockIdx.x * CH;
    const int chunkN = min(CH, N_EDGES - ebase);

    for (int i = t; i < NB; i += 256) cntA[i] = 0;
    __syncthreads();
    for (int i = t; i < chunkN; i += 256)
        atomicAdd(&cntA[dst[ebase + i] >> 6], 1);
    __syncthreads();
    int c[4];
    int s = 0;
#pragma unroll
    for (int q = 0; q < 4; ++q) {
        int idx = t * 4 + q;
        c[q] = (idx < NB) ? cntA[idx] : 0;
        s += c[q];
    }
    part[t] = s;
    __syncthreads();
    for (int d = 1; d < 256; d <<= 1) {
        int u = (t >= d) ? part[t - d] : 0;
        __syncthreads();
        part[t] += u;
        __syncthreads();
    }
    int run = (t > 0) ? part[t - 1] : 0;
#pragma unroll
    for (int q = 0; q < 4; ++q) {
        int idx = t * 4 + q;
        if (idx < NB) {
            lofs[idx] = run;
            run += c[q];
            gbase[idx] = (c[q] > 0) ? atomicAdd(&gcur[idx], c[q]) : 0;
            cntA[idx] = 0;  // reuse as placement cursor
        }
    }
    __syncthreads();
    for (int i = t; i < chunkN; i += 256) {
        int d = dst[ebase + i];
        int sv = src[ebase + i];
        int b = d >> 6;
        int pos = atomicAdd(&cntA[b], 1);
        buf[lofs[b] + pos] = ((unsigned)d << 16) | (unsigned)sv;
    }
    __syncthreads();
    for (int i = t; i < chunkN; i += 256) {
        unsigned v = buf[i];
        int b = (int)(v >> 16) >> 6;
        int q = i - lofs[b];
        int p = gbase[b] + q;
        if (p < CAP) arena[((size_t)b << 11) + p] = v;
    }
}

// ---- pass 2 (fused): bucket finalize | x->fp16 cast | W->fp16 W^T ---------
__global__ __launch_bounds__(256) void k_fill3prep(
    const unsigned* __restrict__ arena, const int* __restrict__ gcur,
    unsigned* __restrict__ packed, float* __restrict__ dinv,
    unsigned short* __restrict__ eidx, const float* __restrict__ x,
    __half* __restrict__ xh, const float* __restrict__ W0,
    const float* __restrict__ W1, const float* __restrict__ W2,
    __half* __restrict__ WT) {
    const int t = threadIdx.x;
    if (blockIdx.x < NB) {
        const int b = blockIdx.x;
        __shared__ int cnt64[64];
        __shared__ int cur64[64];
        if (t < 64) cnt64[t] = 0;
        __syncthreads();
        const int seglen = min(gcur[b], CAP);
        const unsigned* seg = arena + ((size_t)b << 11);
        for (int i = t; i < seglen; i += 256)
            atomicAdd(&cnt64[(seg[i] >> 16) & 63], 1);
        __syncthreads();
        if (t < 64) {  // one wave: prefix scan of 64 counts
            int v = cnt64[t];
            int p = v;
#pragma unroll
            for (int d = 1; d < 64; d <<= 1) {
                int u = __shfl_up(p, d, 64);
                if (t >= d) p += u;
            }
            int excl = p - v;
            int node = b * 64 + t;
            if (node < N_NODES) {
                packed[node] =
                    ((unsigned)((b << 11) + excl) << 11) | (unsigned)v;
                dinv[node] = rsqrtf((float)v + 2.0f);  // improved: +2
            }
            cur64[t] = excl;
        }
        __syncthreads();
        const int base = b << 11;
        for (int i = t; i < seglen; i += 256) {
            unsigned v = seg[i];
            int d = (int)(v >> 16) & 63;
            int pos = atomicAdd(&cur64[d], 1);
            eidx[base + pos] = (unsigned short)(v & 0xFFFFu);
        }
    } else if (blockIdx.x < NB + CAST_BLOCKS) {
        int i = (blockIdx.x - NB) * 256 + t;  // float4-granular, exact
        float4 v = *(const float4*)&x[(size_t)i * 4];
        union { ushort4 u; __half h[4]; } p;
        p.h[0] = __float2half(v.x); p.h[1] = __float2half(v.y);
        p.h[2] = __float2half(v.z); p.h[3] = __float2half(v.w);
        *(ushort4*)&xh[(size_t)i * 4] = p.u;
    } else {
        int idx = blockIdx.x - NB - CAST_BLOCKS;  // 0..191
        int which = idx >> 6;
        const float* W = (which == 0) ? W0 : (which == 1) ? W1 : W2;
        int i = (idx & 63) * 256 + t;  // 16384 per matrix: i = k*128 + n
        int k = i >> 7, n = i & 127;
        int np = ((n & 7) << 4) + (n >> 3);  // inverse of perm(n')=(n'&15)*8+(n'>>4)
        WT[which * 128 * 128 + np * 128 + k] = __float2half(W[i]);
    }
}

// ====== MFMA GEMM: Hs = fp16((Ah @ W) * dinv[row]), 2-plane output =========
__global__ __launch_bounds__(256) void k_gemm_mfma(const __half* __restrict__ Ah,
                                                   const __half* __restrict__ WT,
                                                   const float* __restrict__ dinv,
                                                   __half* __restrict__ hs) {
    const int tid = threadIdx.x;
    const int wave = tid >> 6;
    const int lane = tid & 63;
    const int m = lane & 15;
    const int quad = lane >> 4;
    const int rowA = blockIdx.x * 64 + wave * 16 + m;
    const int rA = (rowA < N_NODES) ? rowA : 0;
    const __half* arow = Ah + (size_t)rA * 128 + quad * 8;

    floatx4 acc[8] = {};
#pragma unroll
    for (int kb = 0; kb < 4; ++kb) {
        half8 af = __builtin_nontemporal_load((const half8*)(arow + kb * 32));
#pragma unroll
        for (int nt = 0; nt < 8; ++nt) {
            half8 bf = *(const half8*)(WT + (size_t)(nt * 16 + m) * 128 +
                                       kb * 32 + quad * 8);
            acc[nt] = __builtin_amdgcn_mfma_f32_16x16x32_f16(af, bf, acc[nt],
                                                             0, 0, 0);
        }
    }
    const int rb = blockIdx.x * 64 + wave * 16 + quad * 4;
    __half* base = hs + (m >> 3) * PLANE2 + (m & 7) * 8;
#pragma unroll
    for (int r = 0; r < 4; ++r) {
        int row = rb + r;
        if (row < N_NODES) {
            float dv = dinv[row];
            union { uintx4 u; __half h[8]; } pk;
#pragma unroll
            for (int nt = 0; nt < 8; ++nt)
                pk.h[nt] = __float2half(acc[nt][r] * dv);
            *(uintx4*)(base + (size_t)row * 64) = pk.u;
        }
    }
}

// ---- dense transform, F_out = 16 (last layer): fp16 in, fp32 out ----------
__global__ __launch_bounds__(256) void k_gemm16(const __half* __restrict__ in,
                                                const float* __restrict__ W,
                                                const float* __restrict__ dinv,
                                                float* __restrict__ hs) {
    __shared__ float Wt[16 * 132];
    const int tid = threadIdx.x;
    for (int i = tid; i < 128 * 16; i += 256) {
        int k = i >> 4, c = i & 15;
        Wt[c * 132 + k] = W[i];
    }
    __syncthreads();
    int gid = blockIdx.x * 256 + tid;  // grid exactly 50000*16
    int r = gid >> 4, c = gid & 15;
    const __half* arow = &in[(size_t)r * 128];
    const float* wrow = &Wt[c * 132];
    float acc = 0.f;
#pragma unroll
    for (int k0 = 0; k0 < 128; k0 += 8) {
        union { uint4 u; __half2 h2[4]; } p;
        p.u = *(const uint4*)&arow[k0];
#pragma unroll
        for (int q = 0; q < 4; ++q) {
            float2 a = __half22float2(p.h2[q]);
            acc += a.x * wrow[k0 + 2 * q] + a.y * wrow[k0 + 2 * q + 1];
        }
    }
    hs[gid] = acc * dinv[r];
}

// ====== 2-plane sliced aggregate + epilogue: 8 lanes/node, staged MLP ======
__device__ __forceinline__ void accv(uint4 t, float* acc) {
    union { uint4 u; __half2 h2[4]; } v;
    v.u = t;
#pragma unroll
    for (int q = 0; q < 4; ++q) {
        float2 w = __half22float2(v.h2[q]);
        acc[2 * q] += w.x;
        acc[2 * q + 1] += w.y;
    }
}
__device__ __forceinline__ void store8_nt(__half* p, const float* o) {
    union { uintx4 u; __half h[8]; } c;
#pragma unroll
    for (int j = 0; j < 8; ++j) c.h[j] = __float2half(o[j]);
    __builtin_nontemporal_store(c.u, (uintx4*)p);
}

// out[r][s*64 + l8*8 ..+8) = relu(dinv*(2*Hs[r]+sum Hs[src]) + b)
// launch_bounds(256,2): allow ~200 VGPR so 8 row-loads stay in flight.
__global__ __launch_bounds__(256, 2) void k_gather_s2(
    const unsigned* __restrict__ packed, const unsigned short* __restrict__ eidx,
    const __half* __restrict__ hs, const float* __restrict__ dinv,
    const float* __restrict__ bias, __half* __restrict__ out) {
    const int s = blockIdx.x & 1;   // plane; round-robin pins planes to XCDs
    const int nb = blockIdx.x >> 1;
    const int t = threadIdx.x;
    const int r = nb * 32 + (t >> 3);
    if (r >= N_NODES) return;
    const int l8 = t & 7;
    const int fl = l8 * 8;
    const __half* plane = hs + s * PLANE2;
    float acc[8];
    {
        union { uint4 u; __half2 h2[4]; } p;
        p.u = *(const uint4*)&plane[(size_t)r * 64 + fl];
#pragma unroll
        for (int q = 0; q < 4; ++q) {
            float2 v = __half22float2(p.h2[q]);
            acc[2 * q] = 2.f * v.x;
            acc[2 * q + 1] = 2.f * v.y;
        }
    }
    unsigned pk = packed[r];
    int i = (int)(pk >> 11);
    int end = i + (int)(pk & 2047u);
    // 16-edge batches: stage 8 rows in regs while next 8 load
    for (; i + 16 <= end; i += 16) {
        int mya = (int)__builtin_nontemporal_load(&eidx[i + l8]);
        int myb = (int)__builtin_nontemporal_load(&eidx[i + 8 + l8]);
        uint4 va[8], vb[8];
#pragma unroll
        for (int j = 0; j < 8; ++j) {
            int s0 = __shfl(mya, j, 8);
            va[j] = *(const uint4*)&plane[(size_t)s0 * 64 + fl];
        }
#pragma unroll
        for (int j = 0; j < 8; ++j) {
            int s0 = __shfl(myb, j, 8);
            vb[j] = *(const uint4*)&plane[(size_t)s0 * 64 + fl];
        }
#pragma unroll
        for (int j = 0; j < 8; ++j) accv(va[j], acc);
#pragma unroll
        for (int j = 0; j < 8; ++j) accv(vb[j], acc);
    }
    for (; i + 8 <= end; i += 8) {
        int mya = (int)__builtin_nontemporal_load(&eidx[i + l8]);
        uint4 va[8];
#pragma unroll
        for (int j = 0; j < 8; ++j) {
            int s0 = __shfl(mya, j, 8);
            va[j] = *(const uint4*)&plane[(size_t)s0 * 64 + fl];
        }
#pragma unroll
        for (int j = 0; j < 8; ++j) accv(va[j], acc);
    }
    if (i < end) {
        int n = end - i;
        int mya = (l8 < n) ? (int)eidx[i + l8] : 0;
        for (int j = 0; j < n; ++j) {
            int s0 = __shfl(mya, j, 8);
            accv(*(const uint4*)&plane[(size_t)s0 * 64 + fl], acc);
        }
    }
    float dv = dinv[r];
    float o[8];
#pragma unroll
    for (int j = 0; j < 8; ++j)
        o[j] = fmaxf(dv * acc[j] + bias[s * 64 + fl + j], 0.f);
    store8_nt(out + (size_t)r * 128 + s * 64 + fl, o);
}

// ====== fp32 gather for the last (F=16) layer ======
__global__ __launch_bounds__(256) void k_gather4(const unsigned* __restrict__ packed,
                                                 const unsigned short* __restrict__ eidx,
                                                 const float* __restrict__ hs,
                                                 const float* __restrict__ dinv,
                                                 const float* __restrict__ bias,
                                                 float* __restrict__ out) {
    int tid = blockIdx.x * 256 + threadIdx.x;
    int r = tid >> 2;
    if (r >= N_NODES) return;
    int l = tid & 3;
    int f = l * 4;
    float4 h = *(const float4*)&hs[(size_t)r * 16 + f];
    float ax = 2.f * h.x, ay = 2.f * h.y, az = 2.f * h.z, aw = 2.f * h.w;
    unsigned pk = packed[r];
    int i = (int)(pk >> 11);
    int end = i + (int)(pk & 2047u);
    for (; i + 4 <= end; i += 4) {
        int my = (int)eidx[i + l];
#pragma unroll
        for (int j = 0; j < 4; ++j) {
            int s = __shfl(my, j, 4);
            float4 v = *(const float4*)&hs[(size_t)s * 16 + f];
            ax += v.x; ay += v.y; az += v.z; aw += v.w;
        }
    }
    if (i < end) {
        int n = end - i;
        int my = (l < n) ? (int)eidx[i + l] : 0;
        for (int j = 0; j < n; ++j) {
            int s = __shfl(my, j, 4);
            float4 v = *(const float4*)&hs[(size_t)s * 16 + f];
            ax += v.x; ay += v.y; az += v.z; aw += v.w;
        }
    }
    float dv = dinv[r];
    float v0 = tanhf(dv * ax + bias[f + 0]);
    float v1 = tanhf(dv * ay + bias[f + 1]);
    float v2 = tanhf(dv * az + bias[f + 2]);
    float v3 = tanhf(dv * aw + bias[f + 3]);
    floatx4 o = {v0, v1, v2, v3};
    __builtin_nontemporal_store(o, (floatx4*)&out[(size_t)r * 16 + f]);
}

extern "C" void kernel_launch(void* const* d_in, const int* in_sizes, int n_in,
                              void* d_out, int out_size, void* d_ws, size_t ws_size,
                              hipStream_t stream) {
    const float* x  = (const float*)d_in[0];
    const int* ei   = (const int*)d_in[1];
    const float* W0 = (const float*)d_in[2];
    const float* b0 = (const float*)d_in[3];
    const float* W1 = (const float*)d_in[4];
    const float* b1 = (const float*)d_in[5];
    const float* W2 = (const float*)d_in[6];
    const float* b2 = (const float*)d_in[7];
    const float* W3 = (const float*)d_in[8];
    const float* b3 = (const float*)d_in[9];
    const int* src = ei;
    const int* dst = ei + N_EDGES;

    // ws layout (16B-aligned):
    __half* A      = (__half*)d_ws;                        // 50000*128 f16
    __half* Hh     = A + (size_t)N_NODES * 128;            // 2 planes of 64
    __half* WT     = Hh + (size_t)N_NODES * 128;           // 3*128*128 f16
    float*  H16    = (float*)(WT + 3 * 128 * 128);         // 50000*16 f32
    float*  dinv   = H16 + (size_t)N_NODES * 16;           // 50000
    unsigned* packed = (unsigned*)(dinv + N_NODES);        // 50000
    int*    gcur   = (int*)(packed + N_NODES);             // 1024 (NB padded)
    unsigned short* eidx = (unsigned short*)(gcur + 1024); // NB*CAP u16
    unsigned* arena = (unsigned*)(eidx + NB * CAP);        // NB*CAP

    // ---- CSR build + prep (every call; ws is re-poisoned) ----
    (void)hipMemsetAsync(gcur, 0, 1024 * sizeof(int), stream);
    k_bucket<<<BUCKET_BLOCKS, 256, 0, stream>>>(src, dst, gcur, arena);
    k_fill3prep<<<FILL_GRID, 256, 0, stream>>>(arena, gcur, packed, dinv,
                                               eidx, x, A, W0, W1, W2, WT);

    const int GB = (N_NODES + 63) / 64;   // mfma gemm blocks (64 rows each)
    const int SGB = 2 * ((N_NODES + 31) / 32);  // sliced gather blocks
    // ---- layer 0 ----
    k_gemm_mfma<<<GB, 256, 0, stream>>>(A, WT, dinv, Hh);
    k_gather_s2<<<SGB, 256, 0, stream>>>(packed, eidx, Hh, dinv, b0, A);
    // ---- layer 1 ----
    k_gemm_mfma<<<GB, 256, 0, stream>>>(A, WT + 128 * 128, dinv, Hh);
    k_gather_s2<<<SGB, 256, 0, stream>>>(packed, eidx, Hh, dinv, b1, A);
    // ---- layer 2 ----
    k_gemm_mfma<<<GB, 256, 0, stream>>>(A, WT + 2 * 128 * 128, dinv, Hh);
    k_gather_s2<<<SGB, 256, 0, stream>>>(packed, eidx, Hh, dinv, b2, A);
    // ---- layer 3 (128 -> 16, tanh) ----
    k_gemm16<<<N_NODES * 16 / 256, 256, 0, stream>>>(A, W3, dinv, H16);
    k_gather4<<<(N_NODES * 4 + 255) / 256, 256, 0, stream>>>(
        packed, eidx, H16, dinv, b3, (float*)d_out);
}